// Round 7
// baseline (305.396 us; speedup 1.0000x reference)
//
#include <hip/hip_runtime.h>
#include <hip/hip_bf16.h>
#include <stdint.h>

// Problem constants (shapes fixed by the reference)
#define DIM 1024
#define NH 16
#define HD 64
#define S_ORIG 8704
#define WIN 512          // L * WINDOW = 256*2

typedef __attribute__((ext_vector_type(8))) short short8;
typedef __attribute__((ext_vector_type(4))) float f32x4;
typedef __attribute__((ext_vector_type(16))) float f32x16;

__device__ __forceinline__ float bf2f(unsigned short u) {
    return __uint_as_float(((unsigned int)u) << 16);
}
__device__ __forceinline__ unsigned short f2bf(float f) {
    unsigned int x = __float_as_uint(f);
    unsigned int r = x + 0x7fffu + ((x >> 16) & 1u);   // RNE
    return (unsigned short)(r >> 16);
}
// two fp32 -> packed bf16x2 in ONE VALU op (T12 recipe; no builtin on gfx950)
__device__ __forceinline__ unsigned int cvtpk(float lo, float hi) {
    unsigned int r;
    asm("v_cvt_pk_bf16_f32 %0, %1, %2" : "=v"(r) : "v"(lo), "v"(hi));
    return r;
}
// exp2 in a single v_exp_f32 (log2e folded into the Q scale by the caller)
__device__ __forceinline__ float fexp2(float x) {
#if __has_builtin(__builtin_amdgcn_exp2f)
    return __builtin_amdgcn_exp2f(x);
#else
    float r;
    asm("v_exp_f32 %0, %1" : "=v"(r) : "v"(x));
    return r;
#endif
}

#define GLD_LDS(gptr, lptr) \
    __builtin_amdgcn_global_load_lds((const __attribute__((address_space(1))) void*)(gptr), \
                                     (__attribute__((address_space(3))) void*)(lptr), 16, 0, 0)

// raw barrier (no compiler-inserted full drains) with compiler memory fences
#define FBAR() do { __asm__ volatile("" ::: "memory"); \
                    __builtin_amdgcn_s_barrier(); \
                    __asm__ volatile("" ::: "memory"); } while (0)

// ---------------- merged prep: fp32->bf16 convert (x) + weight transpose ----------------
__global__ __launch_bounds__(256) void prep(const float* __restrict__ x,
                                            unsigned short* __restrict__ xb,
                                            const float* __restrict__ w0,
                                            const float* __restrict__ w1,
                                            const float* __restrict__ w2,
                                            const float* __restrict__ w3,
                                            unsigned short* __restrict__ wt) {
    __shared__ float ts[64][65];
    const int bx = blockIdx.x;
    const int t = threadIdx.x;
    if (bx < 8704) {
        int i = (bx * 256 + t) * 4;   // total = 8704*1024, exact
        float4 v = *(const float4*)(x + i);
        ushort4 o;
        o.x = f2bf(v.x); o.y = f2bf(v.y); o.z = f2bf(v.z); o.w = f2bf(v.w);
        *(ushort4*)(xb + i) = o;
        return;
    }
    const int b = bx - 8704;
    const int z = b >> 8;
    const int rem = b & 255;
    const int kb = (rem >> 4) * 64, nb = (rem & 15) * 64;
    const float* w = z == 0 ? w0 : z == 1 ? w1 : z == 2 ? w2 : w3;
    unsigned short* o = wt + (size_t)z * DIM * DIM;
    const int c = t & 63, r4 = t >> 6;
#pragma unroll
    for (int rr = 0; rr < 16; rr++) {
        int row = rr * 4 + r4;
        ts[row][c] = w[(size_t)(kb + row) * DIM + nb + c];
    }
    __syncthreads();
#pragma unroll
    for (int rr = 0; rr < 16; rr++) {
        int nl = rr * 4 + r4;
        o[(size_t)(nb + nl) * DIM + kb + c] = f2bf(ts[c][nl]);
    }
}

// ---------------- bf16 MFMA GEMM: C[M,N] = A[M,K] * Bt[N,K]^T + bias ----------------
// R5 (verified): 3-deep pipelined GLD_LDS staging, counted vmcnt(8), raw barriers.
__device__ __forceinline__ void gemm_step(const unsigned short* __restrict__ pa,
                                          const unsigned short* __restrict__ pb,
                                          int wr, int wc, int r, int jsw,
                                          f32x4 acc[4][4]) {
    short8 af[4], bfr[4];
#pragma unroll
    for (int i = 0; i < 4; i++)
        af[i] = *(const short8*)&pa[(wr * 64 + i * 16 + r) * 32 + jsw];
#pragma unroll
    for (int j = 0; j < 4; j++)
        bfr[j] = *(const short8*)&pb[(wc * 64 + j * 16 + r) * 32 + jsw];
#pragma unroll
    for (int i = 0; i < 4; i++)
#pragma unroll
        for (int j = 0; j < 4; j++)
            acc[i][j] = __builtin_amdgcn_mfma_f32_16x16x32_bf16(af[i], bfr[j], acc[i][j], 0, 0, 0);
}

template <int OUTF32>
__global__ __launch_bounds__(256) void gemm_bf16(const unsigned short* __restrict__ A,
                                                 const unsigned short* __restrict__ Bt,
                                                 const float* __restrict__ b0,
                                                 const float* __restrict__ b1,
                                                 const float* __restrict__ b2,
                                                 void* __restrict__ Cout) {
    __shared__ __align__(16) unsigned short As[3][128 * 32];
    __shared__ __align__(16) unsigned short Bs[3][128 * 32];
    const int z = blockIdx.z;
    const unsigned short* B = Bt + (size_t)z * DIM * DIM;
    const float* bias = z == 0 ? b0 : (z == 1 ? b1 : b2);
    const int m0 = blockIdx.x * 128, n0 = blockIdx.y * 128;   // m fastest (XCD locality)
    const int tid = threadIdx.x;
    const int lane = tid & 63, wv = tid >> 6;
    const int wr = wv >> 1, wc = wv & 1;
    const int quad = lane >> 4, r = lane & 15;

    f32x4 acc[4][4];
#pragma unroll
    for (int i = 0; i < 4; i++)
#pragma unroll
        for (int j = 0; j < 4; j++)
#pragma unroll
            for (int t4 = 0; t4 < 4; t4++) acc[i][j][t4] = 0.0f;

    const unsigned short* a_base = A + (size_t)m0 * DIM;
    const unsigned short* b_base = B + (size_t)n0 * DIM;
    const int c0 = wv * 128 + lane;
    const int r0 = c0 >> 2, o0 = (((c0 & 3) ^ ((c0 >> 3) & 3))) * 8;
    const int c1 = c0 + 64;
    const int r1 = c1 >> 2, o1 = (((c1 & 3) ^ ((c1 >> 3) & 3))) * 8;
    const int ld0 = (wv * 128) * 8, ld1 = (wv * 128 + 64) * 8;

    const int jsw = (quad ^ ((r >> 1) & 3)) * 8;

#define ISSUE_STEP(k0_, abuf_, bbuf_) do {                                  \
        GLD_LDS(a_base + (size_t)r0 * DIM + (k0_) + o0, (abuf_) + ld0);     \
        GLD_LDS(a_base + (size_t)r1 * DIM + (k0_) + o1, (abuf_) + ld1);     \
        GLD_LDS(b_base + (size_t)r0 * DIM + (k0_) + o0, (bbuf_) + ld0);     \
        GLD_LDS(b_base + (size_t)r1 * DIM + (k0_) + o1, (bbuf_) + ld1);     \
    } while (0)

    unsigned short *pa0 = &As[0][0], *pa1 = &As[1][0], *pa2 = &As[2][0];
    unsigned short *pb0 = &Bs[0][0], *pb1 = &Bs[1][0], *pb2 = &Bs[2][0];

    // prologue: steps 0 and 32 in flight (8 vmem ops outstanding)
    ISSUE_STEP(0, pa0, pb0);
    ISSUE_STEP(32, pa1, pb1);

#pragma unroll 3
    for (int k0 = 0; k0 < DIM - 64; k0 += 32) {
        FBAR();   // all waves done reading the buffer pa2/pb2 (computed last iter)
        ISSUE_STEP(k0 + 64, pa2, pb2);
        __asm__ volatile("s_waitcnt vmcnt(8)" ::: "memory");   // step k0's 4 ops done
        __builtin_amdgcn_sched_barrier(0);
        FBAR();   // all waves' DMAs for step k0 landed
        gemm_step(pa0, pb0, wr, wc, r, jsw, acc);
        unsigned short* t;
        t = pa0; pa0 = pa1; pa1 = pa2; pa2 = t;
        t = pb0; pb0 = pb1; pb1 = pb2; pb2 = t;
    }
    // peeled tail: no new issues; counted waits shrink 4 -> 0
    __asm__ volatile("s_waitcnt vmcnt(4)" ::: "memory");
    __builtin_amdgcn_sched_barrier(0);
    FBAR();
    gemm_step(pa0, pb0, wr, wc, r, jsw, acc);
    {
        unsigned short* t;
        t = pa0; pa0 = pa1; pa1 = pa2; pa2 = t;
        t = pb0; pb0 = pb1; pb1 = pb2; pb2 = t;
    }
    __asm__ volatile("s_waitcnt vmcnt(0)" ::: "memory");
    __builtin_amdgcn_sched_barrier(0);
    FBAR();
    gemm_step(pa0, pb0, wr, wc, r, jsw, acc);
#undef ISSUE_STEP

    // epilogue: C/D layout col = lane&15, row = quad*4 + reg
#pragma unroll
    for (int i = 0; i < 4; i++) {
        const int row = m0 + wr * 64 + i * 16 + quad * 4;
#pragma unroll
        for (int j = 0; j < 4; j++) {
            const int col = n0 + wc * 64 + j * 16 + r;
            const float bvl = bias[col];
#pragma unroll
            for (int t4 = 0; t4 < 4; t4++) {
                float vv = acc[i][j][t4] + bvl;
                if (OUTF32) {
                    ((float*)Cout)[(size_t)(row + t4) * DIM + col] = vv;
                } else {
                    ((unsigned short*)Cout)[(size_t)z * S_ORIG * DIM + (size_t)(row + t4) * DIM + col] = f2bf(vv);
                }
            }
        }
    }
}

// ---------------- fused RMSNorm + RoPE, wave-per-row (no LDS, no barrier) ----------------
__global__ __launch_bounds__(256) void norm_rope(unsigned short* __restrict__ hq,
                                                 unsigned short* __restrict__ hk,
                                                 const float* __restrict__ gq,
                                                 const float* __restrict__ gk,
                                                 const float* __restrict__ fcos,
                                                 const float* __restrict__ fsin) {
    const int z = blockIdx.y;
    unsigned short* h = z == 0 ? hq : hk;
    const float* g = z == 0 ? gq : gk;
    const int w = threadIdx.x >> 6, lane = threadIdx.x & 63;
    const int srow = blockIdx.x * 4 + w;
    unsigned short* hp = h + (size_t)srow * DIM;
    const int p0 = lane * 8, p1 = 512 + lane * 8;

    union { int4 i4; unsigned short u[8]; } r0, r1, o0, o1;
    r0.i4 = *(const int4*)(hp + p0);
    r1.i4 = *(const int4*)(hp + p1);
    float v[16];
#pragma unroll
    for (int j = 0; j < 8; j++) { v[j] = bf2f(r0.u[j]); v[8 + j] = bf2f(r1.u[j]); }

    float ss = 0.0f;
#pragma unroll
    for (int j = 0; j < 16; j++) ss += v[j] * v[j];
#pragma unroll
    for (int off = 1; off < 64; off <<= 1) ss += __shfl_xor(ss, off, 64);
    const float rinv = rsqrtf(ss * (1.0f / DIM) + 1e-6f);

    float4 ga = *(const float4*)(g + p0), gb = *(const float4*)(g + p0 + 4);
    float4 gc = *(const float4*)(g + p1), gd = *(const float4*)(g + p1 + 4);
    const float* gg[4] = {&ga.x, &gb.x, &gc.x, &gd.x};
#pragma unroll
    for (int q4 = 0; q4 < 4; q4++)
#pragma unroll
        for (int j = 0; j < 4; j++) v[q4 * 4 + j] *= rinv * gg[q4][j];

    const int i0 = (p0 & 63) >> 1;   // pair base within head (mult of 4); same for p1
    float4 cs = *(const float4*)(fcos + (size_t)srow * 32 + i0);
    float4 sn = *(const float4*)(fsin + (size_t)srow * 32 + i0);
    const float* cp = &cs.x;
    const float* sp = &sn.x;
#pragma unroll
    for (int seg = 0; seg < 2; seg++) {
        unsigned short* uo = seg == 0 ? o0.u : o1.u;
#pragma unroll
        for (int pr = 0; pr < 4; pr++) {
            const float a = v[seg * 8 + pr * 2], b = v[seg * 8 + pr * 2 + 1];
            uo[pr * 2]     = f2bf(a * cp[pr] - b * sp[pr]);
            uo[pr * 2 + 1] = f2bf(a * sp[pr] + b * cp[pr]);
        }
    }
    *(int4*)(hp + p0) = o0.i4;
    *(int4*)(hp + p1) = o1.i4;
}

// ---------------- dilated sliding-window attention, 32x32 MFMA flash ----------------
// R6/R7: 32x32x16 MFMA (halves LDS frag reads per FLOP) + in-register P via
// cvt_pk_bf16 + v_permlane32_swap (P LDS round-trip and its lgkmcnt(0) eliminated).
// Block = 4 waves; wave w owns 32 q-rows: tile t0+(w>>1), half w&1. K/V staged once
// per block, shared by all 4 waves (pairing amortization kept). R4 pipeline skeleton:
// K double-buffered GLD_LDS DMA, V loads 1 tile ahead into regs, counted vmcnt(4).
// Layouts (m74, verified): C/D col=lane&31, row=(reg&3)+8*(reg>>2)+4*(lane>>5);
// A/B-op: m(or n)=lane&31, k=(lane>>5)*8+j.
__device__ __forceinline__ void softmax16(f32x16& s, int kk0, int hi4, int qi,
                                          bool edge, float& lsum) {
#pragma unroll
    for (int reg = 0; reg < 16; reg++) {
        float e = fexp2(s[reg]);
        if (edge) {
            const int kj = kk0 + (reg & 3) + 8 * (reg >> 2) + hi4;
            const int dl = qi - kj;
            if (dl > WIN || dl < -WIN) e = 0.0f;
        }
        s[reg] = e;
        lsum += e;
    }
}

// Build one PV B-fragment (16-kk window) from 8 exp'd scores (regs base..base+7).
// v_permlane32_swap(A,B): A' = {A.lo32lanes, B.lo32lanes}, B' = {A.hi, B.hi}.
// Words: w0=A0' (k hi*8+{0,1}), w1=A1' ({2,3}), w2=B0' ({4,5}), w3=B1' ({6,7}).
__device__ __forceinline__ short8 mkfrag(const f32x16& p, int base) {
    unsigned int a0 = cvtpk(p[base + 0], p[base + 1]);
    unsigned int b0 = cvtpk(p[base + 4], p[base + 5]);
    unsigned int a1 = cvtpk(p[base + 2], p[base + 3]);
    unsigned int b1 = cvtpk(p[base + 6], p[base + 7]);
    asm volatile("v_permlane32_swap_b32 %0, %1" : "+v"(a0), "+v"(b0));
    asm volatile("v_permlane32_swap_b32 %0, %1" : "+v"(a1), "+v"(b1));
    union { unsigned int w[4]; short8 s; } u;
    u.w[0] = a0; u.w[1] = a1; u.w[2] = b0; u.w[3] = b1;
    return u.s;
}

// V^T staging: Vt[64 d][64 kk], XOR chunk swizzle (16B chunk c of row r at c^(r&7)).
// vt_d0 is a multiple of 8, so (row&7) is compile-time per dw.
__device__ __forceinline__ void pack_write_v(unsigned short* __restrict__ Vt,
                                             int4 a0i, int4 a1i, int vt_d0, int vkc, int vko) {
    union { int4 i4; unsigned int w[4]; } a0, a1;
    a0.i4 = a0i; a1.i4 = a1i;
#pragma unroll
    for (int dw = 0; dw < 4; dw++) {
        unsigned int lo = __builtin_amdgcn_perm(a1.w[dw], a0.w[dw], 0x05040100u);
        unsigned int hw = __builtin_amdgcn_perm(a1.w[dw], a0.w[dw], 0x07060302u);
        *(unsigned int*)&Vt[(vt_d0 + dw * 2) * 64 + ((vkc ^ (dw * 2)) << 3) + vko] = lo;
        *(unsigned int*)&Vt[(vt_d0 + dw * 2 + 1) * 64 + ((vkc ^ (dw * 2 + 1)) << 3) + vko] = hw;
    }
}

__global__ __launch_bounds__(256) void attn(const unsigned short* __restrict__ qkv,
                                            unsigned short* __restrict__ ob) {
    __shared__ __align__(16) unsigned short Ks[2][64 * 64];   // double-buffered, DMA-staged
    __shared__ __align__(16) unsigned short Vt[64 * 64];      // swizzled V^T

    const int head = blockIdx.x >> 1;
    const int d = blockIdx.x & 1;
    const int t0 = blockIdx.y * 2, t1 = t0 + 1;     // q-tile pair
    const int tid = threadIdx.x;
    const int lane = tid & 63, wv = tid >> 6;
    const int hi = lane >> 5, q32 = lane & 31;
    const int sw8 = (q32 & 7);                       // row-XOR for frag reads

    const unsigned short* qb = qkv;
    const unsigned short* kb = qkv + (size_t)S_ORIG * DIM;
    const unsigned short* vb = qkv + (size_t)2 * S_ORIG * DIM;

    // --- this wave's 32 q-rows; lane owns column q = lane&31 ---
    const int tw = t0 + (wv >> 1);
    const int qi = tw * 64 + (wv & 1) * 32 + q32;
    const int og_q = ((qi >> 8) << 9) + d * 256 + (qi & 255);

    // Q B-op fragments: lane loads its own q-row, d = kd*16 + hi*8 + j
    short8 qf[4];
    {
        const float QSC = 0.125f * 1.44269504088896f;   // softmax scale * log2(e)
        const unsigned short* qrow = qb + (size_t)og_q * DIM + head * HD + hi * 8;
#pragma unroll
        for (int kd = 0; kd < 4; kd++) {
            union { int4 i4; unsigned short u[8]; short8 s8; } iv, ov;
            iv.i4 = *(const int4*)(qrow + kd * 16);
#pragma unroll
            for (int j = 0; j < 8; j++) ov.u[j] = f2bf(bf2f(iv.u[j]) * QSC);
            qf[kd] = ov.s8;
        }
    }

    f32x16 o0, o1;      // O^T: d-tiles 0/1 (32 d each), col q = lane&31
#pragma unroll
    for (int i = 0; i < 16; i++) { o0[i] = 0.0f; o1[i] = 0.0f; }
    float lsum = 0.0f;

    // union of both tiles' windows; kt>=68 zero-pad handled analytically
    const int kt_lo = (t0 - 8 > 0) ? (t0 - 8) : 0;
    const int kt_hi = (t1 + 8 < 67) ? (t1 + 8) : 67;

    // K staging (GLD_LDS): thread tid covers LDS 16B-slot wv*64+lane of each half;
    // row = tid>>3, phys chunk = tid&7 holds global chunk (tid&7)^(row&7).
    const int krow0 = tid >> 3;
    const int kgc = ((tid & 7) ^ (krow0 & 7)) * 8;

    // V^T staging coords
    const int vt_kk = (tid & 31) * 2, vt_d0 = (tid >> 5) * 8;
    const int vkc = vt_kk >> 3, vko = vt_kk & 7;

#define ISSUE_K(kbase_, bufb_) do {                                              \
        const int kj0_ = (kbase_) + krow0;                                       \
        const int ok0_ = ((kj0_ >> 8) << 9) + d * 256 + (kj0_ & 255);            \
        GLD_LDS(kb + (size_t)ok0_ * DIM + head * HD + kgc, (bufb_) + wv * 512);  \
        const int kj1_ = kj0_ + 32;                                              \
        const int ok1_ = ((kj1_ >> 8) << 9) + d * 256 + (kj1_ & 255);            \
        GLD_LDS(kb + (size_t)ok1_ * DIM + head * HD + kgc, (bufb_) + 2048 + wv * 512); \
    } while (0)

#define LOAD_V(kbase_, a0_, a1_) do {                                            \
        const int kj_ = (kbase_) + vt_kk;                                        \
        const int ok_ = ((kj_ >> 8) << 9) + d * 256 + (kj_ & 255);               \
        (a0_) = *(const int4*)(vb + (size_t)ok_ * DIM + head * HD + vt_d0);      \
        (a1_) = *(const int4*)(vb + (size_t)(ok_ + 1) * DIM + head * HD + vt_d0);\
    } while (0)

    // prologue: tile kt_lo in flight (4 vector-mem ops outstanding)
    ISSUE_K(kt_lo * 64, &Ks[0][0]);
    int4 vc0, vc1;
    LOAD_V(kt_lo * 64, vc0, vc1);

    int cur = 0;
    for (int kt = kt_lo; kt <= kt_hi; kt++) {
        const int kbase = kt * 64;
        FBAR();   // A: all waves done reading Ks[cur^1] and Vt before overwrite

        // issue NEXT tile (last iter: redundant re-issue keeps vmcnt count static)
        const int knb = ((kt < kt_hi) ? (kt + 1) : kt_hi) * 64;
        ISSUE_K(knb, &Ks[cur ^ 1][0]);
        int4 vn0, vn1;
        LOAD_V(knb, vn0, vn1);

        // counted wait: 4 newer ops in flight -> previous tile's 4 done
        __asm__ volatile("s_waitcnt vmcnt(4)" ::: "memory");
        __builtin_amdgcn_sched_barrier(0);

        // stage V^T (current tile), swizzled
        pack_write_v(&Vt[0], vc0, vc1, vt_d0, vkc, vko);
        __asm__ volatile("s_waitcnt lgkmcnt(0)" ::: "memory");
        FBAR();   // B: K[cur] DMA-resident + all waves' Vt writes visible

        // wave active iff kt within its tile's window (wave-uniform)
        if (kt >= tw - 8 && kt <= tw + 8) {
            const bool edge = (kt == tw - 8) || (kt == tw + 8);
            const unsigned short* K = &Ks[cur][0];

            // --- S^T[64kk][32q]: A = K rows (kk), B = Q ---
            f32x16 s0, s1;
#pragma unroll
            for (int i = 0; i < 16; i++) { s0[i] = 0.0f; s1[i] = 0.0f; }
#pragma unroll
            for (int kd = 0; kd < 4; kd++) {
                const int c = ((kd * 2 + hi) ^ sw8) << 3;
                short8 k0 = *(const short8*)&K[q32 * 64 + c];
                short8 k1 = *(const short8*)&K[(32 + q32) * 64 + c];
                s0 = __builtin_amdgcn_mfma_f32_32x32x16_bf16(k0, qf[kd], s0, 0, 0, 0);
                s1 = __builtin_amdgcn_mfma_f32_32x32x16_bf16(k1, qf[kd], s1, 0, 0, 0);
            }

            // --- exp2 (fixed-max; scores bounded), edge mask, in-register P frags ---
            const int hi4 = hi * 4;
            softmax16(s0, kbase, hi4, qi, edge, lsum);
            softmax16(s1, kbase + 32, hi4, qi, edge, lsum);
            short8 pf0 = mkfrag(s0, 0), pf1 = mkfrag(s0, 8);
            short8 pf2 = mkfrag(s1, 0), pf3 = mkfrag(s1, 8);

            // --- O^T += V^T * P^T: A = Vt rows (d), B = P frags ---
#pragma unroll
            for (int kw = 0; kw < 4; kw++) {
                const int c = ((kw * 2 + hi) ^ sw8) << 3;
                short8 v0 = *(const short8*)&Vt[q32 * 64 + c];
                short8 v1 = *(const short8*)&Vt[(32 + q32) * 64 + c];
                const short8 pf = kw == 0 ? pf0 : kw == 1 ? pf1 : kw == 2 ? pf2 : pf3;
                o0 = __builtin_amdgcn_mfma_f32_32x32x16_bf16(v0, pf, o0, 0, 0, 0);
                o1 = __builtin_amdgcn_mfma_f32_32x32x16_bf16(v1, pf, o1, 0, 0, 0);
            }
        }

        vc0 = vn0; vc1 = vn1;
        cur ^= 1;
    }
#undef ISSUE_K
#undef LOAD_V

    // keep final (unused) V loads live (vmcnt arithmetic, rule #17), then drain
    __asm__ volatile("" :: "v"(vc0.x), "v"(vc0.y), "v"(vc0.z), "v"(vc0.w),
                          "v"(vc1.x), "v"(vc1.y), "v"(vc1.z), "v"(vc1.w));
    __asm__ volatile("s_waitcnt vmcnt(0)" ::: "memory");

    // --- final l: partner lane (lane^32) holds the other half of kk for same q ---
    lsum += __shfl_xor(lsum, 32, 64);
    // zero-pad keys (dilated pos >= 4352 -> orig >= 8704, K=V=0): exp2(0)=1 each
    {
        const int cnt = (qi + WIN < 4607 ? qi + WIN : 4607) - 4351;
        if (cnt > 0) lsum += (float)cnt;
    }
    const float linv = 1.0f / lsum;

    // --- write O: lane owns q-row og_q; d = dt*32 + g*8 + hi*4 + b ---
    unsigned short* obase = ob + (size_t)og_q * DIM + head * HD + hi * 4;
#pragma unroll
    for (int g = 0; g < 4; g++) {
        ushort4 u0, u1;
        u0.x = f2bf(o0[g * 4 + 0] * linv);
        u0.y = f2bf(o0[g * 4 + 1] * linv);
        u0.z = f2bf(o0[g * 4 + 2] * linv);
        u0.w = f2bf(o0[g * 4 + 3] * linv);
        *(ushort4*)(obase + g * 8) = u0;
        u1.x = f2bf(o1[g * 4 + 0] * linv);
        u1.y = f2bf(o1[g * 4 + 1] * linv);
        u1.z = f2bf(o1[g * 4 + 2] * linv);
        u1.w = f2bf(o1[g * 4 + 3] * linv);
        *(ushort4*)(obase + 32 + g * 8) = u1;
    }
}

// ---------------- launch ----------------
extern "C" void kernel_launch(void* const* d_in, const int* in_sizes, int n_in,
                              void* d_out, int out_size, void* d_ws, size_t ws_size,
                              hipStream_t stream) {
    const float* x    = (const float*)d_in[0];
    const float* fcos = (const float*)d_in[1];
    const float* fsin = (const float*)d_in[2];
    const float* wq   = (const float*)d_in[3];
    const float* bq   = (const float*)d_in[4];
    const float* wk   = (const float*)d_in[5];
    const float* bk   = (const float*)d_in[6];
    const float* wv   = (const float*)d_in[7];
    const float* bv   = (const float*)d_in[8];
    const float* wo   = (const float*)d_in[9];
    const float* bo   = (const float*)d_in[10];
    const float* gq   = (const float*)d_in[11];
    const float* gk   = (const float*)d_in[12];

    char* ws = (char*)d_ws;
    unsigned short* xb = (unsigned short*)(ws);
    unsigned short* wt = (unsigned short*)(ws + 17825792);
    unsigned short* h  = (unsigned short*)(ws + 26214400);
    unsigned short* ob = (unsigned short*)(ws + 79691776);
    float* outp = (float*)d_out;

    prep<<<9728, 256, 0, stream>>>(x, xb, wq, wk, wv, wo, wt);
    gemm_bf16<0><<<dim3(68, 8, 3), 256, 0, stream>>>(xb, wt, bq, bk, bv, (void*)h);
    norm_rope<<<dim3(2176, 2), 256, 0, stream>>>(h, h + (size_t)S_ORIG * DIM, gq, gk, fcos, fsin);
    attn<<<dim3(32, 34), 256, 0, stream>>>(h, ob);
    gemm_bf16<1><<<dim3(68, 8, 1), 256, 0, stream>>>(ob, wt + (size_t)3 * DIM * DIM, bo, bo, bo, (void*)outp);
}